// Round 7
// baseline (994.082 us; speedup 1.0000x reference)
//
#include <hip/hip_runtime.h>

// ---------------- problem constants ----------------
#define NTOT   2097152          // 1024*2048
#define NBLK   1024
#define NTHR   256
#define NIT    8
#define STRIDE (NBLK*NTHR)

// ---------------- ws layout (float-slot offsets) ----------------
#define WS_SUMLR 0
#define WS_SUMD2 1
#define WGAM     2
#define WB4      4     // float4: bdt, bdn, bbg, bbl
#define WSM      8     // 10 x float4: (wdt,wdn,wbg,wbl)[k]  -> 40 slots
#define WBIAS    48    // 40 f32 fused bias row
#define WPACK    88    // 400 uint (half2-packed GRU weights), slots 88..487
#define WEND     488
#define P1       512   // k_partial partials: NBLK*2
#define P2       2560  // k_main partials: NBLK*24

// ---------------- out layout (float offsets) ----------------
#define OFF_DELTA 0
#define OFF_GBAR  (NTOT)
#define OFF_LAM   (5*NTOT)
#define OFF_HP    (9*NTOT)
#define OFF_HT    (19*NTOT)
#define OFF_NU    (19*NTOT+5)
#define OFF_NUBAR (20*NTOT+5)
#define OFF_GI    (21*NTOT+5)

typedef _Float16 h2t __attribute__((ext_vector_type(2)));

__device__ __forceinline__ float fast_rcp(float x)  { return __builtin_amdgcn_rcpf(x); }
__device__ __forceinline__ float fast_rsq(float x)  { return __builtin_amdgcn_rsqf(x); }
__device__ __forceinline__ float fast_sqrt(float x) { return __builtin_amdgcn_sqrtf(x); }
__device__ __forceinline__ float sigmoidf(float x) {
  return fast_rcp(1.0f + __expf(-x));
}
__device__ __forceinline__ float tanh_f(float x) {
  const float e = __expf(-2.0f * x);
  return fmaf(2.0f, fast_rcp(1.0f + e), -1.0f);
}

#if defined(__has_builtin)
#if __has_builtin(__builtin_amdgcn_fdot2)
#define HAVE_FDOT2 1
#endif
#endif

__device__ __forceinline__ float fdot2(h2t a, h2t b, float c) {
#ifdef HAVE_FDOT2
  return __builtin_amdgcn_fdot2(a, b, c, false);
#else
  return c + (float)a.x * (float)b.x + (float)a.y * (float)b.y;
#endif
}
__device__ __forceinline__ h2t bch2(unsigned int u) {
  return __builtin_bit_cast(h2t, u);
}

// fused-weight element (k = feature row 0..19, j = output col 0..39)
//   rows 0..8  : x-features (pk), cols 30..39 are zero
//   rows 9..18 : h-features (prk), cols 20..29 zero, cols 30..39 = prk cols 20..29
//   row  19    : zero pad
__device__ __forceinline__ float wfe(int k, int j,
                                     const float* __restrict__ pk,
                                     const float* __restrict__ prk) {
  if (k >= 19) return 0.f;
  if (k < 9)  return (j < 30) ? pk[k*30 + j] : 0.f;
  const int kk = k - 9;
  if (j < 20) return prk[kk*30 + j];
  if (j < 30) return 0.f;
  return prk[kk*30 + (j - 10)];
}

// ================= pass 1: partial sums of lr and d_theta^2 =================
__global__ __launch_bounds__(NTHR) void k_partial(
    const float* __restrict__ hparam,
    const float* __restrict__ lr,
    const float* __restrict__ wdt,
    const float* __restrict__ bdt,
    float* __restrict__ pout) {
  float w[10];
  #pragma unroll
  for (int k = 0; k < 10; ++k) w[k] = wdt[k];
  const float b0 = bdt[0];
  const int tid = blockIdx.x * NTHR + threadIdx.x;
  const float2* hp2 = (const float2*)hparam;
  float s_lr = 0.f, s_d2 = 0.f;
  #pragma unroll 1
  for (int it = 0; it < NIT; ++it) {
    const int i = tid + it * STRIDE;
    float d = b0;
    #pragma unroll
    for (int c = 0; c < 5; ++c) {
      const float2 v = hp2[i*5 + c];
      d = fmaf(v.x, w[2*c],   d);
      d = fmaf(v.y, w[2*c+1], d);
    }
    s_d2 = fmaf(d, d, s_d2);
    s_lr += lr[i];
  }
  #pragma unroll
  for (int off = 32; off > 0; off >>= 1) {
    s_lr += __shfl_down(s_lr, off);
    s_d2 += __shfl_down(s_d2, off);
  }
  __shared__ float lred[4][2];
  const int wid = threadIdx.x >> 6, lane = threadIdx.x & 63;
  if (lane == 0) { lred[wid][0] = s_lr; lred[wid][1] = s_d2; }
  __syncthreads();
  if (threadIdx.x == 0) {
    pout[blockIdx.x*2 + 0] = lred[0][0]+lred[1][0]+lred[2][0]+lred[3][0];
    pout[blockIdx.x*2 + 1] = lred[0][1]+lred[1][1]+lred[2][1]+lred[3][1];
  }
}

// ====== prep: pack f16 GRU weights, fused bias, small-dot table, finalize sums ======
__global__ void k_prep(
    const float* __restrict__ pk,
    const float* __restrict__ prk,
    const float* __restrict__ pb,
    const float* __restrict__ wdt,
    const float* __restrict__ bdt,
    const float* __restrict__ wdn,
    const float* __restrict__ bdn,
    const float* __restrict__ wbg,
    const float* __restrict__ bbg,
    const float* __restrict__ wbl,
    const float* __restrict__ bbl,
    const float* __restrict__ ht,
    const float* __restrict__ hg,
    const float* __restrict__ gam,
    float* __restrict__ ws) {
  const int t = threadIdx.x;
  // packed GRU weights: pair p (features 2p,2p+1), col j
  for (int idx = t; idx < 400; idx += NTHR) {
    const int p = idx / 40, j = idx - p*40;
    h2t v;
    v.x = (_Float16)wfe(2*p,     j, pk, prk);
    v.y = (_Float16)wfe(2*p + 1, j, pk, prk);
    ((unsigned int*)ws)[WPACK + idx] = __builtin_bit_cast(unsigned int, v);
  }
  // fused bias row (f32): j<20: xb[j]+pb1[j]; 20..29: xb[j]; 30..39: pb1[j-10]
  if (t < 40) {
    const int j = t;
    float v;
    if (j < 30) {
      float xb = pb[j];
      #pragma unroll
      for (int k = 0; k < 5; ++k) xb = fmaf(ht[k], pk[(9+k)*30 + j], xb);
      #pragma unroll
      for (int k = 0; k < 5; ++k) xb = fmaf(hg[k], pk[(14+k)*30 + j], xb);
      v = (j < 20) ? (xb + pb[30 + j]) : xb;
    } else {
      v = pb[20 + j];   // pb1[j-10]
    }
    ws[WBIAS + j] = v;
  }
  if (t < 10) {
    ws[WSM + t*4 + 0] = wdt[t];
    ws[WSM + t*4 + 1] = wdn[t];
    ws[WSM + t*4 + 2] = wbg[t];
    ws[WSM + t*4 + 3] = wbl[t];
  }
  if (t == 0) {
    ws[WGAM]  = gam[0];
    ws[WB4+0] = bdt[0]; ws[WB4+1] = bdn[0];
    ws[WB4+2] = bbg[0]; ws[WB4+3] = bbl[0];
  }
  // finalize the two global sums from P1
  float a = 0.f, b = 0.f;
  for (int idx = t; idx < NBLK; idx += NTHR) {
    a += ws[P1 + 2*idx];
    b += ws[P1 + 2*idx + 1];
  }
  #pragma unroll
  for (int off = 32; off > 0; off >>= 1) {
    a += __shfl_down(a, off);
    b += __shfl_down(b, off);
  }
  __shared__ float lred[4][2];
  const int wid = t >> 6, lane = t & 63;
  if (lane == 0) { lred[wid][0] = a; lred[wid][1] = b; }
  __syncthreads();
  if (t == 0) {
    ws[WS_SUMLR] = lred[0][0]+lred[1][0]+lred[2][0]+lred[3][0];
    ws[WS_SUMD2] = lred[0][1]+lred[1][1]+lred[2][1]+lred[3][1];
  }
}

// ================= main per-element kernel =================
__global__ __launch_bounds__(NTHR, 4) void k_main(
    const float* __restrict__ grads,
    const float* __restrict__ gbar,
    const float* __restrict__ lam,
    const float* __restrict__ hparam,
    const float* __restrict__ nubar,
    const float* __restrict__ lr,
    const float* __restrict__ cw,      // ws
    float* __restrict__ pout,          // ws + P2
    float* __restrict__ out) {
  __shared__ __align__(16) unsigned int s_w2[400];
  __shared__ __align__(16) float s_sm[40];
  __shared__ __align__(16) float s_bias[40];
  for (int idx = threadIdx.x; idx < 400; idx += NTHR)
    s_w2[idx] = ((const unsigned int*)cw)[WPACK + idx];
  if (threadIdx.x < 40) {
    s_sm[threadIdx.x]   = cw[WSM + threadIdx.x];
    s_bias[threadIdx.x] = cw[WBIAS + threadIdx.x];
  }
  __syncthreads();

  const float mean_lr = cw[WS_SUMLR] * (1.0f / (float)NTOT);
  const float scale   = (float)NTOT * fast_rsq(cw[WS_SUMD2]);
  const float gamma   = cw[WGAM];
  const float bdt_b = cw[WB4+0], bdn_b = cw[WB4+1];
  const float bbg_b = cw[WB4+2], bbl_b = cw[WB4+3];

  float am0=0,am1=0,am2=0,am3=0, ag0=0,ag1=0,ag2=0,ag3=0, anu=0;
  float ah[10];
  #pragma unroll
  for (int j = 0; j < 10; ++j) ah[j] = 0.f;

  const int tid = blockIdx.x * NTHR + threadIdx.x;
  const float2* hp2  = (const float2*)hparam;
  float2*       hpo2 = (float2*)(out + OFF_HP);
  const uint4*  w4   = (const uint4*)s_w2;
  const float4* sm4  = (const float4*)s_sm;
  const float4* b4p  = (const float4*)s_bias;

  #pragma unroll 1
  for (int it = 0; it < NIT; ++it) {
    const int i = tid + it * STRIDE;
    // -------- loads --------
    float h[10];
    #pragma unroll
    for (int c = 0; c < 5; ++c) {
      const float2 v = hp2[i*5 + c];
      h[2*c]   = v.x;
      h[2*c+1] = v.y;
    }
    const float g   = grads[i];
    const float lri = lr[i];
    const float nb  = nubar[i];

    // -------- 4 small dots (LDS float4 broadcast) --------
    float ddt = bdt_b, ddn = bdn_b, dbg = bbg_b, dbl = bbl_b;
    #pragma unroll
    for (int k = 0; k < 10; ++k) {
      const float4 w = sm4[k];
      ddt = fmaf(h[k], w.x, ddt);
      ddn = fmaf(h[k], w.y, ddn);
      dbg = fmaf(h[k], w.z, dbg);
      dbl = fmaf(h[k], w.w, dbl);
    }
    const float bg = sigmoidf(dbg);
    const float bl = sigmoidf(dbl);

    // -------- per-scale EMA, m, gamma_feat --------
    const float g2 = g * g;
    float x[9], ll[4];
    float b1 = bg, b2 = bl;
    #pragma unroll
    for (int s = 0; s < 4; ++s) {
      if (s) { b1 = fast_sqrt(b1); b2 = fast_sqrt(b2); }
      const float go = gbar[s*NTOT + i];
      const float lo = lam [s*NTOT + i];
      const float gb = fmaf(b1, go - g,  g);
      const float lm = fmaf(b2, lo - g2, g2);
      out[OFF_GBAR + s*NTOT + i] = gb;
      out[OFF_LAM  + s*NTOT + i] = lm;
      x[s]  = gb * fast_rsq(lm);
      ll[s] = __logf(lm);
    }
    am0 += x[0]; am1 += x[1]; am2 += x[2]; am3 += x[3];
    const float llm = (ll[0]+ll[1]+ll[2]+ll[3]) * 0.25f;
    x[4] = ll[0]-llm; x[5] = ll[1]-llm; x[6] = ll[2]-llm; x[7] = ll[3]-llm;
    ag0 += x[4]; ag1 += x[5]; ag2 += x[6]; ag3 += x[7];

    // -------- nu / nu_bar_new / delta_theta --------
    const float nu = ddn + nb;
    out[OFF_NU    + i] = nu;
    out[OFF_NUBAR + i] = fmaf(gamma, nb - nu, nu);
    out[OFF_DELTA + i] = __expf(lri) * ddt * scale;
    const float nurel = lri - mean_lr;
    x[8] = nurel;
    anu += nurel;

    // -------- pack features to half2: (x0,x1)..(x8,h0),(h1,h2)..(h9,0) --------
    h2t f2[10];
    #pragma unroll
    for (int p = 0; p < 4; ++p) {
      f2[p].x = (_Float16)x[2*p]; f2[p].y = (_Float16)x[2*p+1];
    }
    f2[4].x = (_Float16)x[8]; f2[4].y = (_Float16)h[0];
    #pragma unroll
    for (int p = 5; p < 9; ++p) {
      f2[p].x = (_Float16)h[2*p-9]; f2[p].y = (_Float16)h[2*p-8];
    }
    f2[9].x = (_Float16)h[9]; f2[9].y = (_Float16)0.f;

    // -------- GRU matmul: acc[0..19]=z|r fused, [20..29]=xh, [30..39]=rh --------
    float acc[40];
    #pragma unroll
    for (int q = 0; q < 10; ++q) {
      const float4 b = b4p[q];
      acc[4*q+0]=b.x; acc[4*q+1]=b.y; acc[4*q+2]=b.z; acc[4*q+3]=b.w;
    }
    #pragma unroll
    for (int p = 0; p < 10; ++p) {
      const h2t fp = f2[p];
      #pragma unroll
      for (int q = 0; q < 10; ++q) {
        const uint4 w = w4[p*10 + q];
        acc[4*q+0] = fdot2(fp, bch2(w.x), acc[4*q+0]);
        acc[4*q+1] = fdot2(fp, bch2(w.y), acc[4*q+1]);
        acc[4*q+2] = fdot2(fp, bch2(w.z), acc[4*q+2]);
        acc[4*q+3] = fdot2(fp, bch2(w.w), acc[4*q+3]);
      }
    }

    // -------- gates (h unpacked from f2 to cut register pressure) --------
    float hn[10];
    #pragma unroll
    for (int u = 0; u < 10; ++u) {
      const int fi = 9 + u, p = fi >> 1;
      const float hu = (float)((fi & 1) ? f2[p].y : f2[p].x);
      const float z   = sigmoidf(acc[u]);
      const float r   = sigmoidf(acc[10+u]);
      const float pre = fmaf(r, acc[30+u], acc[20+u]);
      const float th  = tanh_f(pre);
      hn[u] = fmaf(z, hu - th, th);
      ah[u] += hn[u];
    }
    #pragma unroll
    for (int jj = 0; jj < 5; ++jj)
      hpo2[i*5 + jj] = make_float2(hn[2*jj], hn[2*jj+1]);
  }

  // -------- block reduction of the 19 partials --------
  float acc[19];
  acc[0]=am0; acc[1]=am1; acc[2]=am2; acc[3]=am3;
  acc[4]=ag0; acc[5]=ag1; acc[6]=ag2; acc[7]=ag3;
  acc[8]=anu;
  #pragma unroll
  for (int j = 0; j < 10; ++j) acc[9+j] = ah[j];
  #pragma unroll
  for (int off = 32; off > 0; off >>= 1) {
    #pragma unroll
    for (int v = 0; v < 19; ++v) acc[v] += __shfl_down(acc[v], off);
  }
  __shared__ float lred[4][19];
  const int wid = threadIdx.x >> 6, lane = threadIdx.x & 63;
  if (lane == 0) {
    #pragma unroll
    for (int v = 0; v < 19; ++v) lred[wid][v] = acc[v];
  }
  __syncthreads();
  if (threadIdx.x < 19) {
    const int v = threadIdx.x;
    pout[blockIdx.x*24 + v] = lred[0][v]+lred[1][v]+lred[2][v]+lred[3][v];
  }
}

// ================= final: 19 means, tensor GRU, tail outputs =================
__global__ void k_final(
    const float* __restrict__ tk,
    const float* __restrict__ trk,
    const float* __restrict__ tb,
    const float* __restrict__ ht,
    const float* __restrict__ hg,
    const float* __restrict__ p2,
    float* __restrict__ out) {
  const int t = threadIdx.x;
  float acc[19];
  #pragma unroll
  for (int v = 0; v < 19; ++v) acc[v] = 0.f;
  for (int b = t; b < NBLK; b += NTHR) {
    #pragma unroll
    for (int v = 0; v < 19; ++v) acc[v] += p2[b*24 + v];
  }
  #pragma unroll
  for (int off = 32; off > 0; off >>= 1) {
    #pragma unroll
    for (int v = 0; v < 19; ++v) acc[v] += __shfl_down(acc[v], off);
  }
  __shared__ float lred[4][19];
  const int wid = t >> 6, lane = t & 63;
  if (lane == 0) {
    #pragma unroll
    for (int v = 0; v < 19; ++v) lred[wid][v] = acc[v];
  }
  __syncthreads();
  if (t == 0) {
    const float invn = 1.0f / (float)NTOT;
    float ti[24];
    #pragma unroll
    for (int v = 0; v < 19; ++v)
      ti[v] = (lred[0][v]+lred[1][v]+lred[2][v]+lred[3][v]) * invn;
    #pragma unroll
    for (int k = 0; k < 5; ++k) ti[19+k] = hg[k];
    float h5[5];
    #pragma unroll
    for (int k = 0; k < 5; ++k) h5[k] = ht[k];

    float xs[15];
    #pragma unroll
    for (int j = 0; j < 15; ++j) {
      float v = tb[j];
      #pragma unroll
      for (int k = 0; k < 24; ++k) v = fmaf(ti[k], tk[k*15 + j], v);
      xs[j] = v;
    }
    float htn[5];
    #pragma unroll
    for (int j = 0; j < 5; ++j) {
      float rz = tb[15 + j], rr = tb[20 + j], rh = tb[25 + j];
      #pragma unroll
      for (int k = 0; k < 5; ++k) {
        rz = fmaf(h5[k], trk[k*15 + j],      rz);
        rr = fmaf(h5[k], trk[k*15 + 5 + j],  rr);
        rh = fmaf(h5[k], trk[k*15 + 10 + j], rh);
      }
      const float z  = sigmoidf(xs[j] + rz);
      const float r  = sigmoidf(xs[5+j] + rr);
      const float hh = tanh_f(xs[10+j] + r*rh);
      htn[j] = fmaf(z, h5[j] - hh, hh);
      out[OFF_HT + j] = htn[j];
    }
    #pragma unroll
    for (int v = 0; v < 19; ++v) out[OFF_GI + v] = ti[v];
    #pragma unroll
    for (int k = 0; k < 5; ++k)  out[OFF_GI + 19 + k] = htn[k];
  }
}

extern "C" void kernel_launch(void* const* d_in, const int* in_sizes, int n_in,
                              void* d_out, int out_size, void* d_ws, size_t ws_size,
                              hipStream_t stream) {
  const float* grads  = (const float*)d_in[1];
  const float* gbar   = (const float*)d_in[2];
  const float* lam    = (const float*)d_in[3];
  const float* hparam = (const float*)d_in[4];
  const float* ht     = (const float*)d_in[5];
  const float* hg     = (const float*)d_in[6];
  const float* nubar  = (const float*)d_in[7];
  const float* lr     = (const float*)d_in[8];
  const float* pk     = (const float*)d_in[9];
  const float* prk    = (const float*)d_in[10];
  const float* pb     = (const float*)d_in[11];
  const float* tk     = (const float*)d_in[12];
  const float* trk    = (const float*)d_in[13];
  const float* tb     = (const float*)d_in[14];
  const float* wdt    = (const float*)d_in[15];
  const float* bdt    = (const float*)d_in[16];
  const float* wdn    = (const float*)d_in[17];
  const float* bdn    = (const float*)d_in[18];
  const float* wbg    = (const float*)d_in[19];
  const float* bbg    = (const float*)d_in[20];
  const float* wbl    = (const float*)d_in[21];
  const float* bbl    = (const float*)d_in[22];
  const float* gam    = (const float*)d_in[23];
  float* ws  = (float*)d_ws;
  float* out = (float*)d_out;

  k_partial<<<NBLK, NTHR, 0, stream>>>(hparam, lr, wdt, bdt, ws + P1);
  k_prep<<<1, NTHR, 0, stream>>>(pk, prk, pb, wdt, bdt, wdn, bdn,
                                 wbg, bbg, wbl, bbl, ht, hg, gam, ws);
  k_main<<<NBLK, NTHR, 0, stream>>>(grads, gbar, lam, hparam, nubar, lr,
                                    ws, ws + P2, out);
  k_final<<<1, NTHR, 0, stream>>>(tk, trk, tb, ht, hg, ws + P2, out);
}